// Round 11
// baseline (176.806 us; speedup 1.0000x reference)
//
#include <hip/hip_runtime.h>
#include <hip/hip_bf16.h>
#include <math.h>

// x[32,512,64,64] f32; w1[32,512] f32; w2[512,32] f32.
// Bit-replication of the numpy-fp32 reference pipeline (round-4 PASSED, absmax 0.0).
// ROUND 11 = PROBE ROUND: pool launched 3x (idempotent: g_y rewritten with the
// same values). dur delta vs ~100.8 baseline = 2x warm-pool time. Round-9 probe
// already fixed gather at 38.7us (BW ceiling); this splits the remaining ~20us
// between pool and se+launch-gaps. Pool reverted to round-8 register version
// (round-10 LDS staging was neutral-to-worse).

#define C1 512
#define C2 256
#define CMID 32
#define HW 4096   // 64*64
#define B 32

typedef float f32x4 __attribute__((ext_vector_type(4)));

__device__ float g_y[B * C1];     // pooled means, fp32 (numpy-bit-exact)
__device__ int   g_idx[B * C2];   // top-256 channel indices per batch

// ---------------- Kernel 1: numpy-pairwise mean, one wave per channel ----------------
// numpy pairwise_sum(4096): 32 blocks of 128; per block 8 accumulators r_j,
// r_j += a[8i+j] (i=1..15), combine ((r0+r1)+(r2+r3))+((r4+r5)+(r6+r7)); perfect
// binary tree over blocks. Lane-pair (2m,2m+1) owns block m; lane holds r[4h..4h+3].
__global__ __launch_bounds__(256) void pool_np_kernel(const float* __restrict__ x) {
    int bc = blockIdx.x * 4 + (threadIdx.x >> 6);   // channel 0..16383
    int L = threadIdx.x & 63;
    const float* a = x + (size_t)bc * HW;
    const float* base = a + (L >> 1) * 128 + (L & 1) * 4;
    f32x4 r = *(const f32x4*)base;
#pragma unroll
    for (int i = 1; i < 16; ++i) {
        f32x4 v = *(const f32x4*)(base + 8 * i);
        r.x = __fadd_rn(r.x, v.x);
        r.y = __fadd_rn(r.y, v.y);
        r.z = __fadd_rn(r.z, v.z);
        r.w = __fadd_rn(r.w, v.w);
    }
    float s = __fadd_rn(__fadd_rn(r.x, r.y), __fadd_rn(r.z, r.w));
    s = __fadd_rn(s, __shfl_xor(s, 1));    // lane0 chain + lane1 chain
    s = __fadd_rn(s, __shfl_xor(s, 2));    // perfect tree over the 32 blocks
    s = __fadd_rn(s, __shfl_xor(s, 4));
    s = __fadd_rn(s, __shfl_xor(s, 8));
    s = __fadd_rn(s, __shfl_xor(s, 16));
    s = __fadd_rn(s, __shfl_xor(s, 32));
    if (L == 0) g_y[bc] = __fdiv_rn(s, 4096.0f);
}

// numpy einsum SSE sum_of_products_contig_two: single __m128 accumulator;
// per 8-chunk: acc += p[0:4]; acc += p[4:8]; final (L0+L1)+(L2+L3).
__device__ __forceinline__ float dot_sse(const float* __restrict__ u,
                                         const float* __restrict__ v, int n) {
    float L0 = 0.f, L1 = 0.f, L2 = 0.f, L3 = 0.f;
    for (int c = 0; c < n; c += 8) {
        L0 = __fadd_rn(L0, __fmul_rn(u[c+0], v[c+0]));
        L1 = __fadd_rn(L1, __fmul_rn(u[c+1], v[c+1]));
        L2 = __fadd_rn(L2, __fmul_rn(u[c+2], v[c+2]));
        L3 = __fadd_rn(L3, __fmul_rn(u[c+3], v[c+3]));
        L0 = __fadd_rn(L0, __fmul_rn(u[c+4], v[c+4]));
        L1 = __fadd_rn(L1, __fmul_rn(u[c+5], v[c+5]));
        L2 = __fadd_rn(L2, __fmul_rn(u[c+6], v[c+6]));
        L3 = __fadd_rn(L3, __fmul_rn(u[c+7], v[c+7]));
    }
    return __fadd_rn(__fadd_rn(L0, L1), __fadd_rn(L2, L3));
}

// ---------------- Kernel 2: SE MLP (fp32 numpy-replica) + stable rank ----------------
__global__ __launch_bounds__(512) void se_np_kernel(const float* __restrict__ w1,
                                                    const float* __restrict__ w2) {
    int b = blockIdx.x;        // 0..31
    int t = threadIdx.x;       // 0..511
    __shared__ float ys[C1];
    __shared__ float hs[CMID];
    __shared__ float ss[C1];

    ys[t] = g_y[b * C1 + t];
    __syncthreads();

    // Layer 1: 32 rows x 4 independent SSE chains (numpy L0..L3), thread = (row,k)
    if (t < CMID * 4) {
        int row = t >> 2, k = t & 3;
        const float* v = w1 + row * C1;
        float Lk = 0.f;
        for (int c = 0; c < C1; c += 8) {
            Lk = __fadd_rn(Lk, __fmul_rn(ys[c + k],     v[c + k]));
            Lk = __fadd_rn(Lk, __fmul_rn(ys[c + 4 + k], v[c + 4 + k]));
        }
        Lk = __fadd_rn(Lk, __shfl_xor(Lk, 1));   // (L0+L1),(L2+L3)
        Lk = __fadd_rn(Lk, __shfl_xor(Lk, 2));   // final combine
        if (k == 0) hs[row] = Lk > 0.0f ? Lk : 0.0f;   // np.maximum(z, 0)
    }
    __syncthreads();

    {
        float z = dot_sse(hs, w2 + t * CMID, CMID);
        float e = (float)exp((double)(-z));      // correctly-rounded fp32 exp
        ss[t] = __fdiv_rn(1.0f, __fadd_rn(1.0f, e));
    }
    __syncthreads();

    // stable argsort(-s): rank = #{s' > s} + #{equal with smaller index}
    float sc = ss[t];
    int rank = 0;
#pragma unroll 8
    for (int c = 0; c < C1; ++c) {
        float v = ss[c];
        rank += (int)((v > sc) || (v == sc && c < t));
    }
    if (rank < C2) g_idx[b * C2 + rank] = t;
}

// ---------------- Kernel 3: gather, half-plane per block (full residency) ----------------
__global__ __launch_bounds__(256) void gather_kernel(const float* __restrict__ x,
                                                     float* __restrict__ out) {
    int bid  = blockIdx.x >> 1;                // plane 0..1023 (b*C2 + r)
    int half = blockIdx.x & 1;                 // 0: first 8 KB, 1: second 8 KB
    int b = bid >> 8;
    int c = g_idx[bid];
    const f32x4* src = (const f32x4*)(x + ((size_t)(b * C1 + c)) * HW);
    f32x4* dst = (f32x4*)(out + (size_t)bid * HW);
    int j = half * 512 + threadIdx.x;          // float4 index within plane
    f32x4 v0 = src[j];
    f32x4 v1 = src[j + 256];
    __builtin_nontemporal_store(v0, &dst[j]);
    __builtin_nontemporal_store(v1, &dst[j + 256]);
}

extern "C" void kernel_launch(void* const* d_in, const int* in_sizes, int n_in,
                              void* d_out, int out_size, void* d_ws, size_t ws_size,
                              hipStream_t stream) {
    const float* x  = (const float*)d_in[0];
    const float* w1 = (const float*)d_in[1];
    const float* w2 = (const float*)d_in[2];
    float* out = (float*)d_out;

    // PROBE: 3x identical pool (idempotent). delta vs single-pool = 2x warm-pool.
    pool_np_kernel<<<B * C1 / 4, 256, 0, stream>>>(x);
    pool_np_kernel<<<B * C1 / 4, 256, 0, stream>>>(x);
    pool_np_kernel<<<B * C1 / 4, 256, 0, stream>>>(x);
    se_np_kernel<<<B, C1, 0, stream>>>(w1, w2);
    gather_kernel<<<B * C2 * 2, 256, 0, stream>>>(x, out);
}

// Round 12
// 100.688 us; speedup vs baseline: 1.7560x; 1.7560x over previous
//
#include <hip/hip_runtime.h>
#include <hip/hip_bf16.h>
#include <math.h>

// x[32,512,64,64] f32; w1[32,512] f32; w2[512,32] f32.
// Bit-replication of the numpy-fp32 reference pipeline (round-4 PASSED, absmax 0.0):
//   y = np.mean(x,(2,3))             -> numpy pairwise_sum (128-blocks, 8 accums, tree)
//   h = relu(np.einsum('bc,rc->br')) -> SSE sum-of-products (mod-4 lanes, (L0+L1)+(L2+L3))
//   s = 1/(1+np.exp(-z))             -> correctly-rounded fp32 exp via fp64, fp32 add/div
//   idx = argsort(-s, stable)[:, :256]; out = take_along_axis(x, idx)
// Round 12: se kernel de-latency-chained. Round-11 probe: pool=38.0us (at HBM
// floor), gather=38.7us (at floor, round 9) => se+gaps ~= 24us. se's layer-1 had
// 64 serialized global-load->dependent-add hops (w1 inside the chain). Fix:
// stage w1 in LDS (coalesced, padded rows), prefetch w2 into registers before
// the barrier. Add ORDER unchanged everywhere -> still bit-exact.

#define C1 512
#define C2 256
#define CMID 32
#define HW 4096   // 64*64
#define B 32
#define W1PAD 516  // 512 + 4-float pad: layer-1 read = 2-way bank alias (free)

typedef float f32x4 __attribute__((ext_vector_type(4)));

__device__ float g_y[B * C1];     // pooled means, fp32 (numpy-bit-exact)
__device__ int   g_idx[B * C2];   // top-256 channel indices per batch

// ---------------- Kernel 1: numpy-pairwise mean, one wave per channel ----------------
// numpy pairwise_sum(4096): 32 blocks of 128; per block 8 accumulators r_j,
// r_j += a[8i+j] (i=1..15), combine ((r0+r1)+(r2+r3))+((r4+r5)+(r6+r7)); perfect
// binary tree over blocks. Lane-pair (2m,2m+1) owns block m; lane holds r[4h..4h+3].
// Measured at HBM floor (38.0us warm, round-11 probe) -- do not touch.
__global__ __launch_bounds__(256) void pool_np_kernel(const float* __restrict__ x) {
    int bc = blockIdx.x * 4 + (threadIdx.x >> 6);   // channel 0..16383
    int L = threadIdx.x & 63;
    const float* a = x + (size_t)bc * HW;
    const float* base = a + (L >> 1) * 128 + (L & 1) * 4;
    f32x4 r = *(const f32x4*)base;
#pragma unroll
    for (int i = 1; i < 16; ++i) {
        f32x4 v = *(const f32x4*)(base + 8 * i);
        r.x = __fadd_rn(r.x, v.x);
        r.y = __fadd_rn(r.y, v.y);
        r.z = __fadd_rn(r.z, v.z);
        r.w = __fadd_rn(r.w, v.w);
    }
    float s = __fadd_rn(__fadd_rn(r.x, r.y), __fadd_rn(r.z, r.w));
    s = __fadd_rn(s, __shfl_xor(s, 1));    // lane0 chain + lane1 chain
    s = __fadd_rn(s, __shfl_xor(s, 2));    // perfect tree over the 32 blocks
    s = __fadd_rn(s, __shfl_xor(s, 4));
    s = __fadd_rn(s, __shfl_xor(s, 8));
    s = __fadd_rn(s, __shfl_xor(s, 16));
    s = __fadd_rn(s, __shfl_xor(s, 32));
    if (L == 0) g_y[bc] = __fdiv_rn(s, 4096.0f);
}

// ---------------- Kernel 2: SE MLP (fp32 numpy-replica) + stable rank ----------------
__global__ __launch_bounds__(512) void se_np_kernel(const float* __restrict__ w1,
                                                    const float* __restrict__ w2) {
    int b = blockIdx.x;        // 0..31
    int t = threadIdx.x;       // 0..511
    __shared__ float ys[C1];
    __shared__ float hs[CMID];
    __shared__ float ss[C1];
    __shared__ float w1s[CMID * W1PAD];   // 66 KB: w1 staged, rows padded +4

    // Prefetch this thread's w2 row into registers (overlaps staging below;
    // removes global latency from the layer-2 dependent chain).
    f32x4 w2r[8];
#pragma unroll
    for (int i = 0; i < 8; ++i)
        w2r[i] = ((const f32x4*)(w2 + t * CMID))[i];

    // Coalesced stage of w1 (16384 floats) into padded LDS rows.
#pragma unroll
    for (int i = 0; i < 8; ++i) {
        int u = i * 512 + t;               // f32x4 unit index in w1
        int row  = u >> 7;                 // /128 units per row
        int col4 = u & 127;
        f32x4 v = ((const f32x4*)w1)[u];
        *(f32x4*)&w1s[row * W1PAD + col4 * 4] = v;   // W1PAD%4==0 -> aligned
    }
    ys[t] = g_y[b * C1 + t];
    __syncthreads();

    // Layer 1: 32 rows x 4 independent SSE chains (numpy L0..L3), thread = (row,k).
    // Chain arithmetic identical to numpy; source is LDS (pipelined ds_reads).
    if (t < CMID * 4) {
        int row = t >> 2, k = t & 3;
        const float* wr = &w1s[row * W1PAD];
        float Lk = 0.f;
#pragma unroll
        for (int c = 0; c < C1; c += 8) {
            Lk = __fadd_rn(Lk, __fmul_rn(ys[c + k],     wr[c + k]));
            Lk = __fadd_rn(Lk, __fmul_rn(ys[c + 4 + k], wr[c + 4 + k]));
        }
        Lk = __fadd_rn(Lk, __shfl_xor(Lk, 1));   // (L0+L1),(L2+L3)
        Lk = __fadd_rn(Lk, __shfl_xor(Lk, 2));   // final combine
        if (k == 0) hs[row] = Lk > 0.0f ? Lk : 0.0f;   // np.maximum(z, 0)
    }
    __syncthreads();

    // Layer 2: numpy SSE dot over CMID=32 from registers (w2r) + LDS hs.
    // Exact chunk order: c in {0,8,16,24}: lanes L0..L3 <- c+0..3 then c+4..7.
    {
        float L0 = 0.f, L1 = 0.f, L2 = 0.f, L3 = 0.f;
#pragma unroll
        for (int i = 0; i < 8; i += 2) {
            L0 = __fadd_rn(L0, __fmul_rn(hs[i * 4 + 0], w2r[i].x));
            L1 = __fadd_rn(L1, __fmul_rn(hs[i * 4 + 1], w2r[i].y));
            L2 = __fadd_rn(L2, __fmul_rn(hs[i * 4 + 2], w2r[i].z));
            L3 = __fadd_rn(L3, __fmul_rn(hs[i * 4 + 3], w2r[i].w));
            L0 = __fadd_rn(L0, __fmul_rn(hs[i * 4 + 4], w2r[i + 1].x));
            L1 = __fadd_rn(L1, __fmul_rn(hs[i * 4 + 5], w2r[i + 1].y));
            L2 = __fadd_rn(L2, __fmul_rn(hs[i * 4 + 6], w2r[i + 1].z));
            L3 = __fadd_rn(L3, __fmul_rn(hs[i * 4 + 7], w2r[i + 1].w));
        }
        float z = __fadd_rn(__fadd_rn(L0, L1), __fadd_rn(L2, L3));
        float e = (float)exp((double)(-z));      // correctly-rounded fp32 exp
        ss[t] = __fdiv_rn(1.0f, __fadd_rn(1.0f, e));
    }
    __syncthreads();

    // stable argsort(-s): rank = #{s' > s} + #{equal with smaller index}
    float sc = ss[t];
    int rank = 0;
#pragma unroll 8
    for (int c = 0; c < C1; ++c) {
        float v = ss[c];
        rank += (int)((v > sc) || (v == sc && c < t));
    }
    if (rank < C2) g_idx[b * C2 + rank] = t;
}

// ---------------- Kernel 3: gather, half-plane per block (full residency) ----------------
// Measured at BW floor (38.7us warm, round-9 probe) -- do not touch.
__global__ __launch_bounds__(256) void gather_kernel(const float* __restrict__ x,
                                                     float* __restrict__ out) {
    int bid  = blockIdx.x >> 1;                // plane 0..1023 (b*C2 + r)
    int half = blockIdx.x & 1;                 // 0: first 8 KB, 1: second 8 KB
    int b = bid >> 8;
    int c = g_idx[bid];
    const f32x4* src = (const f32x4*)(x + ((size_t)(b * C1 + c)) * HW);
    f32x4* dst = (f32x4*)(out + (size_t)bid * HW);
    int j = half * 512 + threadIdx.x;          // float4 index within plane
    f32x4 v0 = src[j];
    f32x4 v1 = src[j + 256];
    __builtin_nontemporal_store(v0, &dst[j]);
    __builtin_nontemporal_store(v1, &dst[j + 256]);
}

extern "C" void kernel_launch(void* const* d_in, const int* in_sizes, int n_in,
                              void* d_out, int out_size, void* d_ws, size_t ws_size,
                              hipStream_t stream) {
    const float* x  = (const float*)d_in[0];
    const float* w1 = (const float*)d_in[1];
    const float* w2 = (const float*)d_in[2];
    float* out = (float*)d_out;

    pool_np_kernel<<<B * C1 / 4, 256, 0, stream>>>(x);
    se_np_kernel<<<B, C1, 0, stream>>>(w1, w2);
    gather_kernel<<<B * C2 * 2, 256, 0, stream>>>(x, out);
}